// Round 3
// baseline (213.983 us; speedup 1.0000x reference)
//
#include <hip/hip_runtime.h>

typedef __bf16 bf16;
typedef __attribute__((ext_vector_type(4))) bf16 bf16x4;
typedef __attribute__((ext_vector_type(8))) bf16 bf16x8;
typedef __attribute__((ext_vector_type(4))) float f32x4;

#define MFMA16(a, b, c) __builtin_amdgcn_mfma_f32_16x16x32_bf16(a, b, c, 0, 0, 0)

constexpr int Bb = 4, Ss = 4096, Ee = 1024, Hh = 128;
constexpr int Mrows = Bb * Ss;  // 16384

// ---------------------------------------------------------------------------
// Kernel 0: W prep. Transpose W [E,H] f32 -> Wt [3][H][E] bf16.
// grid (E/16, 3), block 256.
// ---------------------------------------------------------------------------
__global__ __launch_bounds__(256) void wprep_kernel(
    const float* __restrict__ Wq, const float* __restrict__ Wk,
    const float* __restrict__ Wv, bf16* __restrict__ Wt)
{
    __shared__ bf16 Sb[16][136];
    const int w = blockIdx.y;
    const float* W = (w == 0) ? Wq : (w == 1) ? Wk : Wv;
    const int k0 = blockIdx.x * 16;
    const int t = threadIdx.x;
    {
        int r = t >> 4, cg = (t & 15) * 8;
        const float4* src = (const float4*)(W + (size_t)(k0 + r) * Hh + cg);
        float4 v0 = src[0], v1 = src[1];
        bf16x4 o0, o1;
        o0[0] = (bf16)v0.x; o0[1] = (bf16)v0.y; o0[2] = (bf16)v0.z; o0[3] = (bf16)v0.w;
        o1[0] = (bf16)v1.x; o1[1] = (bf16)v1.y; o1[2] = (bf16)v1.z; o1[3] = (bf16)v1.w;
        *(bf16x4*)&Sb[r][cg] = o0;
        *(bf16x4*)&Sb[r][cg + 4] = o1;
    }
    __syncthreads();
    {
        int h = t >> 1, kseg = (t & 1) * 8;
        bf16x8 v;
        #pragma unroll
        for (int e = 0; e < 8; ++e) v[e] = Sb[kseg + e][h];
        *(bf16x8*)&Wt[((size_t)w * Hh + h) * Ee + k0 + kseg] = v;
    }
}

// ---------------------------------------------------------------------------
// Kernel 1: QKV projection. grid (Mrows/128, 3), block 256 (4 waves).
// Block computes 128 rows x 128 cols of one projection. V written TRANSPOSED
// globally: Vtg[b][h][s].  Q pre-scaled by 1/sqrt(H).
// ---------------------------------------------------------------------------
__global__ __launch_bounds__(256, 4) void proj_kernel(
    const float* __restrict__ embds, const bf16* __restrict__ Wt,
    const float* __restrict__ bq, const float* __restrict__ bk,
    const float* __restrict__ bv,
    bf16* __restrict__ Qb, bf16* __restrict__ Kb, bf16* __restrict__ Vtg)
{
    __shared__ bf16 As[128][72];
    __shared__ bf16 Bs[128][72];

    const int w = blockIdx.y;
    const float* bias = (w == 0) ? bq : (w == 1) ? bk : bv;
    const int t = threadIdx.x;
    const int wv = t >> 6, lane = t & 63, lo = lane & 15, hi = lane >> 4;
    const int m0 = blockIdx.x * 128;

    f32x4 acc[2][8];
    #pragma unroll
    for (int rf = 0; rf < 2; ++rf)
        #pragma unroll
        for (int f = 0; f < 8; ++f) acc[rf][f] = f32x4{0.f, 0.f, 0.f, 0.f};

    const int arow = t >> 1, acg = (t & 1) * 32;

    for (int k0 = 0; k0 < Ee; k0 += 64) {
        // stage A: 128x64 f32 -> bf16
        {
            const float4* src = (const float4*)(embds + (size_t)(m0 + arow) * Ee + k0 + acg);
            #pragma unroll
            for (int j = 0; j < 8; ++j) {
                float4 v = src[j];
                bf16x4 o; o[0] = (bf16)v.x; o[1] = (bf16)v.y; o[2] = (bf16)v.z; o[3] = (bf16)v.w;
                *(bf16x4*)&As[arow][acg + j * 4] = o;
            }
        }
        // stage B: 128 rows x 64 k, uint4 copies
        #pragma unroll
        for (int rep = 0; rep < 4; ++rep) {
            int idx = rep * 256 + t;
            int row = idx >> 3, c = idx & 7;
            *(uint4*)&Bs[row][c * 8] =
                *(const uint4*)&Wt[((size_t)w * Hh + row) * Ee + k0 + c * 8];
        }
        __syncthreads();
        #pragma unroll
        for (int kk = 0; kk < 2; ++kk) {
            bf16x8 a0 = *(const bf16x8*)&As[wv * 32 + lo][kk * 32 + hi * 8];
            bf16x8 a1 = *(const bf16x8*)&As[wv * 32 + 16 + lo][kk * 32 + hi * 8];
            #pragma unroll
            for (int f = 0; f < 8; ++f) {
                bf16x8 b = *(const bf16x8*)&Bs[f * 16 + lo][kk * 32 + hi * 8];
                acc[0][f] = MFMA16(a0, b, acc[0][f]);
                acc[1][f] = MFMA16(a1, b, acc[1][f]);
            }
        }
        __syncthreads();
    }
    const float scale = (w == 0) ? 0.08838834764831843f : 1.0f;
    if (w == 2) {
        // V transposed: Vtg[b][h][s]
        const int mb = m0 >> 12, s0l = m0 & 4095;
        #pragma unroll
        for (int f = 0; f < 8; ++f) {
            int h = f * 16 + lo;
            float bvv = bias[h];
            #pragma unroll
            for (int rf = 0; rf < 2; ++rf)
                #pragma unroll
                for (int i = 0; i < 4; ++i) {
                    int s = s0l + wv * 32 + rf * 16 + hi * 4 + i;
                    Vtg[((size_t)mb * Hh + h) * Ss + s] = (bf16)(acc[rf][f][i] + bvv);
                }
        }
    } else {
        bf16* dst = (w == 0) ? Qb : Kb;
        #pragma unroll
        for (int f = 0; f < 8; ++f) {
            int col = f * 16 + lo;
            float bvv = bias[col];
            #pragma unroll
            for (int rf = 0; rf < 2; ++rf)
                #pragma unroll
                for (int i = 0; i < 4; ++i) {
                    int row = m0 + wv * 32 + rf * 16 + hi * 4 + i;
                    dst[(size_t)row * Hh + col] = (bf16)((acc[rf][f][i] + bvv) * scale);
                }
        }
    }
}

// ---------------------------------------------------------------------------
// Kernel 2: split-KV causal flash attention, swapped QK^T.
// grid (S/64, B, NC), block 256 (4 waves, 16 q-rows each).
// Chunk c handles tiles {c, c+NC, c+2NC, ...} <= qb (balanced).
// ---------------------------------------------------------------------------
__global__ __launch_bounds__(256, 3) void attn_kernel(
    const bf16* __restrict__ Qb, const bf16* __restrict__ Kb,
    const bf16* __restrict__ Vtg,
    float* __restrict__ Opart, float* __restrict__ Mpart, float* __restrict__ Lpart,
    int NC)
{
    __shared__ bf16 Ks[64][136];   // K tile, stride 272B (read groups balanced)
    __shared__ bf16 Vt[128][64];   // V^T tile, (h&7)-XOR swizzled 16B chunks
    __shared__ bf16 Ps[4][16][72]; // wave-private P[q][kv]

    const int t = threadIdx.x;
    const int wv = t >> 6, lane = t & 63, lo = lane & 15, hi = lane >> 4;
    const int qb = blockIdx.x, b = blockIdx.y, c = blockIdx.z;
    if (c > qb) return;
    const int q0 = qb * 64;
    const size_t base = (size_t)b * Ss * Hh;
    const size_t vbase = (size_t)b * Hh * Ss;

    // Q fragments (B-operand of swapped QK^T) hoisted to registers
    bf16x8 qf[4];
    #pragma unroll
    for (int kk = 0; kk < 4; ++kk)
        qf[kk] = *(const bf16x8*)(Qb + base + (size_t)(q0 + wv * 16 + lo) * Hh + kk * 32 + hi * 8);

    f32x4 acc[8];
    #pragma unroll
    for (int f = 0; f < 8; ++f) acc[f] = f32x4{0.f, 0.f, 0.f, 0.f};
    float M_ = -INFINITY, L_ = 0.f;   // state for q-row (wv*16 + lo), replicated over hi

    uint4 kr[4], vr[4];
    auto issue = [&](int tile) {
        const int kv0 = tile * 64;
        #pragma unroll
        for (int rep = 0; rep < 4; ++rep) {
            int ci = rep * 256 + t;
            int r = ci >> 4, c8 = ci & 15;
            kr[rep] = *(const uint4*)(Kb + base + (size_t)(kv0 + r) * Hh + c8 * 8);
        }
        #pragma unroll
        for (int rep = 0; rep < 4; ++rep) {
            int idx = rep * 256 + t;
            int h = idx >> 3, cc = idx & 7;
            vr[rep] = *(const uint4*)(Vtg + vbase + (size_t)h * Ss + kv0 + cc * 8);
        }
    };

    issue(c);
    for (int tile = c; tile <= qb; tile += NC) {
        __syncthreads();   // previous tile's LDS reads done
        #pragma unroll
        for (int rep = 0; rep < 4; ++rep) {
            int ci = rep * 256 + t;
            int r = ci >> 4, c8 = ci & 15;
            *(uint4*)&Ks[r][c8 * 8] = kr[rep];
        }
        #pragma unroll
        for (int rep = 0; rep < 4; ++rep) {
            int idx = rep * 256 + t;
            int h = idx >> 3, cc = idx & 7;
            *(uint4*)&Vt[h][(cc * 8) ^ ((h & 7) << 3)] = vr[rep];
        }
        int tn = tile + NC;
        if (tn <= qb) issue(tn);   // hide next tile's loads under compute
        __syncthreads();

        // S^T = K Q^T : D[kv][q], kv = f*16+hi*4+i, q = lo
        f32x4 sv[4];
        #pragma unroll
        for (int f = 0; f < 4; ++f) sv[f] = f32x4{0.f, 0.f, 0.f, 0.f};
        #pragma unroll
        for (int kk = 0; kk < 4; ++kk) {
            #pragma unroll
            for (int f = 0; f < 4; ++f) {
                bf16x8 kf = *(const bf16x8*)&Ks[f * 16 + lo][kk * 32 + hi * 8];
                sv[f] = MFMA16(kf, qf[kk], sv[f]);
            }
        }
        if (tile == qb) {   // diagonal tile: mask kv > q (local indices, kv0==q0)
            int qg = wv * 16 + lo;
            #pragma unroll
            for (int f = 0; f < 4; ++f)
                #pragma unroll
                for (int i = 0; i < 4; ++i)
                    if (f * 16 + hi * 4 + i > qg) sv[f][i] = -INFINITY;
        }
        // online softmax: lane owns 16 kv-entries of row q=lo; reduce in-lane + 2 shuffles
        float pm = -INFINITY;
        #pragma unroll
        for (int f = 0; f < 4; ++f)
            pm = fmaxf(pm, fmaxf(fmaxf(sv[f][0], sv[f][1]), fmaxf(sv[f][2], sv[f][3])));
        pm = fmaxf(pm, __shfl_xor(pm, 16));
        pm = fmaxf(pm, __shfl_xor(pm, 32));
        float nM = fmaxf(M_, pm);
        float scn = __expf(M_ - nM);
        float rs = 0.f;
        #pragma unroll
        for (int f = 0; f < 4; ++f)
            #pragma unroll
            for (int i = 0; i < 4; ++i) {
                float e = __expf(sv[f][i] - nM);
                sv[f][i] = e;
                rs += e;
            }
        rs += __shfl_xor(rs, 16);
        rs += __shfl_xor(rs, 32);
        L_ = L_ * scn + rs;
        M_ = nM;
        // rescale O: acc row q' = hi*4+i needs sc of lane lo=q' (same hi-group)
        #pragma unroll
        for (int i = 0; i < 4; ++i) {
            float si = __shfl(scn, (lane & 48) + hi * 4 + i);
            #pragma unroll
            for (int f = 0; f < 8; ++f) acc[f][i] *= si;
        }
        // P -> wave-private LDS as P[q][kv]
        #pragma unroll
        for (int f = 0; f < 4; ++f)
            #pragma unroll
            for (int i = 0; i < 4; ++i)
                Ps[wv][lo][f * 16 + hi * 4 + i] = (bf16)sv[f][i];
        // O += P V
        #pragma unroll
        for (int kk = 0; kk < 2; ++kk) {
            bf16x8 pa = *(const bf16x8*)&Ps[wv][lo][kk * 32 + hi * 8];
            #pragma unroll
            for (int f = 0; f < 8; ++f) {
                int row = f * 16 + lo;
                bf16x8 vf = *(const bf16x8*)&Vt[row][(kk * 32 + hi * 8) ^ ((row & 7) << 3)];
                acc[f] = MFMA16(pa, vf, acc[f]);
            }
        }
    }
    // write unnormalized partials
    const size_t pb = (((size_t)b * 64 + qb) * NC + c) * 64;
    #pragma unroll
    for (int f = 0; f < 8; ++f)
        #pragma unroll
        for (int i = 0; i < 4; ++i) {
            int row = wv * 16 + hi * 4 + i;
            Opart[(pb + row) * 128 + f * 16 + lo] = acc[f][i];
        }
    if (hi == 0) {
        Mpart[pb + wv * 16 + lo] = M_;
        Lpart[pb + wv * 16 + lo] = L_;
    }
}

// ---------------------------------------------------------------------------
// Kernel 3: combine chunk partials. grid (S/64, B), block 256.
// ---------------------------------------------------------------------------
__global__ __launch_bounds__(256) void reduce_kernel(
    const float* __restrict__ Opart, const float* __restrict__ Mpart,
    const float* __restrict__ Lpart, float* __restrict__ out, int NC)
{
    __shared__ float wexp[4][64];
    __shared__ float invL[64];
    const int qb = blockIdx.x, b = blockIdx.y, t = threadIdx.x;
    const int nact = min(NC, qb + 1);
    const size_t pb = ((size_t)b * 64 + qb) * NC * 64;
    if (t < 64) {
        float Mstar = -INFINITY;
        for (int c = 0; c < nact; ++c) Mstar = fmaxf(Mstar, Mpart[pb + c * 64 + t]);
        float Ls = 0.f;
        for (int c = 0; c < nact; ++c) {
            float wc = __expf(Mpart[pb + c * 64 + t] - Mstar);
            wexp[c][t] = wc;
            Ls += wc * Lpart[pb + c * 64 + t];
        }
        invL[t] = 1.f / Ls;
    }
    __syncthreads();
    #pragma unroll
    for (int rep = 0; rep < 8; ++rep) {
        int idx = rep * 256 + t;
        int row = idx >> 5, c4 = (idx & 31) * 4;
        float ox = 0.f, oy = 0.f, oz = 0.f, ow = 0.f;
        for (int c = 0; c < nact; ++c) {
            float wc = wexp[c][row];
            float4 v = *(const float4*)(Opart + (pb + (size_t)c * 64 + row) * 128 + c4);
            ox += wc * v.x; oy += wc * v.y; oz += wc * v.z; ow += wc * v.w;
        }
        float il = invL[row];
        float4 o = make_float4(ox * il, oy * il, oz * il, ow * il);
        *(float4*)(out + ((size_t)b * Ss + qb * 64 + row) * 128 + c4) = o;
    }
}

extern "C" void kernel_launch(void* const* d_in, const int* in_sizes, int n_in,
                              void* d_out, int out_size, void* d_ws, size_t ws_size,
                              hipStream_t stream) {
    (void)in_sizes; (void)n_in; (void)out_size;
    const float* embds = (const float*)d_in[0];
    const float* Wq = (const float*)d_in[1];
    const float* bq = (const float*)d_in[2];
    const float* Wk = (const float*)d_in[3];
    const float* bk = (const float*)d_in[4];
    const float* Wv = (const float*)d_in[5];
    const float* bv = (const float*)d_in[6];

    char* ws = (char*)d_ws;
    size_t off = 0;
    bf16* Qb  = (bf16*)(ws + off); off += (size_t)Mrows * Hh * 2;
    bf16* Kb  = (bf16*)(ws + off); off += (size_t)Mrows * Hh * 2;
    bf16* Vtg = (bf16*)(ws + off); off += (size_t)Mrows * Hh * 2;
    bf16* Wt  = (bf16*)(ws + off); off += (size_t)3 * Hh * Ee * 2;

    int NC = 4;
    {
        auto need = [&](int nc) -> size_t {
            return off + (size_t)Bb * 64 * nc * 64 * 128 * 4
                       + (size_t)Bb * 64 * nc * 64 * 4 * 2;
        };
        if (need(NC) > ws_size) NC = 2;
        if (need(NC) > ws_size) NC = 1;
    }
    float* Opart = (float*)(ws + off);
    size_t osz = (size_t)Bb * 64 * NC * 64 * 128 * 4;
    float* Mp = (float*)(ws + off + osz);
    float* Lp = Mp + (size_t)Bb * 64 * NC * 64;

    wprep_kernel<<<dim3(Ee / 16, 3), 256, 0, stream>>>(Wq, Wk, Wv, Wt);
    proj_kernel<<<dim3(Mrows / 128, 3), 256, 0, stream>>>(embds, Wt, bq, bk, bv, Qb, Kb, Vtg);
    attn_kernel<<<dim3(Ss / 64, Bb, NC), 256, 0, stream>>>(Qb, Kb, Vtg, Opart, Mp, Lp, NC);
    reduce_kernel<<<dim3(Ss / 64, Bb), 256, 0, stream>>>(Opart, Mp, Lp, (float*)d_out, NC);
}

// Round 4
// 114.367 us; speedup vs baseline: 1.8710x; 1.8710x over previous
//
#include <hip/hip_runtime.h>

typedef __bf16 bf16;
typedef __attribute__((ext_vector_type(4))) bf16 bf16x4;
typedef __attribute__((ext_vector_type(8))) bf16 bf16x8;
typedef __attribute__((ext_vector_type(4))) float f32x4;

#define MFMA16(a, b, c) __builtin_amdgcn_mfma_f32_16x16x32_bf16(a, b, c, 0, 0, 0)

constexpr int Bb = 4, Ss = 4096, Ee = 1024, Hh = 128;
constexpr int Mrows = Bb * Ss;  // 16384

// ---------------------------------------------------------------------------
// Kernel 0: W prep. Transpose W [E,H] f32 -> Wt [3][H][E] bf16.
// grid (E/16, 3), block 256.
// ---------------------------------------------------------------------------
__global__ __launch_bounds__(256) void wprep_kernel(
    const float* __restrict__ Wq, const float* __restrict__ Wk,
    const float* __restrict__ Wv, bf16* __restrict__ Wt)
{
    __shared__ bf16 Sb[16][136];
    const int w = blockIdx.y;
    const float* W = (w == 0) ? Wq : (w == 1) ? Wk : Wv;
    const int k0 = blockIdx.x * 16;
    const int t = threadIdx.x;
    {
        int r = t >> 4, cg = (t & 15) * 8;
        const float4* src = (const float4*)(W + (size_t)(k0 + r) * Hh + cg);
        float4 v0 = src[0], v1 = src[1];
        bf16x4 o0, o1;
        o0[0] = (bf16)v0.x; o0[1] = (bf16)v0.y; o0[2] = (bf16)v0.z; o0[3] = (bf16)v0.w;
        o1[0] = (bf16)v1.x; o1[1] = (bf16)v1.y; o1[2] = (bf16)v1.z; o1[3] = (bf16)v1.w;
        *(bf16x4*)&Sb[r][cg] = o0;
        *(bf16x4*)&Sb[r][cg + 4] = o1;
    }
    __syncthreads();
    {
        int h = t >> 1, kseg = (t & 1) * 8;
        bf16x8 v;
        #pragma unroll
        for (int e = 0; e < 8; ++e) v[e] = Sb[kseg + e][h];
        *(bf16x8*)&Wt[((size_t)w * Hh + h) * Ee + k0 + kseg] = v;
    }
}

// ---------------------------------------------------------------------------
// Kernel 1: fused QKV projection. grid (Mrows/64), block 256 (4 waves).
// A staged once per k-iter, reused for Q,K,V. V written TRANSPOSED:
// Vtg[b][h][s]. Q pre-scaled by 1/sqrt(H).
// ---------------------------------------------------------------------------
__global__ __launch_bounds__(256) void proj_kernel(
    const float* __restrict__ embds, const bf16* __restrict__ Wt,
    const float* __restrict__ bq, const float* __restrict__ bk,
    const float* __restrict__ bv,
    bf16* __restrict__ Qb, bf16* __restrict__ Kb, bf16* __restrict__ Vtg)
{
    __shared__ bf16 As[64][72];
    __shared__ bf16 Bs[3][128][72];

    const int t = threadIdx.x;
    const int wv = t >> 6, lane = t & 63, lo = lane & 15, hi = lane >> 4;
    const int m0 = blockIdx.x * 64;

    f32x4 acc[3][8];
    #pragma unroll
    for (int w = 0; w < 3; ++w)
        #pragma unroll
        for (int f = 0; f < 8; ++f) acc[w][f] = f32x4{0.f, 0.f, 0.f, 0.f};

    const int arow = t >> 2, acg = (t & 3) * 16;

    for (int k0 = 0; k0 < Ee; k0 += 64) {
        // stage A: 64x64 f32 -> bf16
        {
            const float4* src = (const float4*)(embds + (size_t)(m0 + arow) * Ee + k0 + acg);
            #pragma unroll
            for (int j = 0; j < 4; ++j) {
                float4 v = src[j];
                bf16x4 o; o[0] = (bf16)v.x; o[1] = (bf16)v.y; o[2] = (bf16)v.z; o[3] = (bf16)v.w;
                *(bf16x4*)&As[arow][acg + j * 4] = o;
            }
        }
        // stage B: 3 x 128 rows x 64 k, uint4 copies from bf16 Wt (L2-resident)
        #pragma unroll
        for (int rep = 0; rep < 12; ++rep) {
            int idx = rep * 256 + t;             // 0..3071
            int w = idx >> 10, row = (idx >> 3) & 127, c = idx & 7;
            *(uint4*)&Bs[w][row][c * 8] =
                *(const uint4*)&Wt[((size_t)w * Hh + row) * Ee + k0 + c * 8];
        }
        __syncthreads();
        #pragma unroll
        for (int kk = 0; kk < 2; ++kk) {
            bf16x8 a = *(const bf16x8*)&As[wv * 16 + lo][kk * 32 + hi * 8];
            #pragma unroll
            for (int w = 0; w < 3; ++w)
                #pragma unroll
                for (int f = 0; f < 8; ++f) {
                    bf16x8 b = *(const bf16x8*)&Bs[w][f * 16 + lo][kk * 32 + hi * 8];
                    acc[w][f] = MFMA16(a, b, acc[w][f]);
                }
        }
        __syncthreads();
    }
    // epilogue
    {   // Q (scaled)
        #pragma unroll
        for (int f = 0; f < 8; ++f) {
            int col = f * 16 + lo;
            float bvv = bq[col];
            #pragma unroll
            for (int i = 0; i < 4; ++i) {
                int row = m0 + wv * 16 + hi * 4 + i;
                Qb[(size_t)row * Hh + col] =
                    (bf16)((acc[0][f][i] + bvv) * 0.08838834764831843f);
            }
        }
    }
    {   // K
        #pragma unroll
        for (int f = 0; f < 8; ++f) {
            int col = f * 16 + lo;
            float bvv = bk[col];
            #pragma unroll
            for (int i = 0; i < 4; ++i) {
                int row = m0 + wv * 16 + hi * 4 + i;
                Kb[(size_t)row * Hh + col] = (bf16)(acc[1][f][i] + bvv);
            }
        }
    }
    {   // V transposed: Vtg[b][h][s]
        const int mb = m0 >> 12, s0l = m0 & 4095;
        #pragma unroll
        for (int f = 0; f < 8; ++f) {
            int h = f * 16 + lo;
            float bvv = bv[h];
            #pragma unroll
            for (int i = 0; i < 4; ++i) {
                int s = s0l + wv * 16 + hi * 4 + i;
                Vtg[((size_t)mb * Hh + h) * Ss + s] = (bf16)(acc[2][f][i] + bvv);
            }
        }
    }
}

// ---------------------------------------------------------------------------
// Kernel 2: split-KV causal flash attention, swapped QK^T.
// grid (S/64, B, NC), block 256 (4 waves, 16 q-rows each).
// Chunk c handles tiles {c, c+NC, c+2NC, ...} <= qb (balanced).
// Staging uses NAMED registers (no arrays/lambdas -> no scratch demotion).
// ---------------------------------------------------------------------------
__global__ __launch_bounds__(256, 3) void attn_kernel(
    const bf16* __restrict__ Qb, const bf16* __restrict__ Kb,
    const bf16* __restrict__ Vtg,
    float* __restrict__ Opart, float* __restrict__ Mpart, float* __restrict__ Lpart,
    int NC)
{
    __shared__ bf16 Ks[64][136];   // K tile, stride 272B
    __shared__ bf16 Vt[128][64];   // V^T tile, (h&7)-XOR swizzled 16B chunks
    __shared__ bf16 Ps[4][16][72]; // wave-private P[q][kv]

    const int t = threadIdx.x;
    const int wv = t >> 6, lane = t & 63, lo = lane & 15, hi = lane >> 4;
    const int qb = blockIdx.x, b = blockIdx.y, c = blockIdx.z;
    if (c > qb) return;
    const int q0 = qb * 64;
    const size_t base = (size_t)b * Ss * Hh;
    const size_t vbase = (size_t)b * Hh * Ss;

    // per-thread staging pointers (rep offsets are compile-time constants)
    const bf16* kg = Kb + base + (size_t)(t >> 4) * Hh + (t & 15) * 8;
    const bf16* vg = Vtg + vbase + (size_t)(t >> 3) * Ss + (t & 7) * 8;
    bf16* ksl = &Ks[t >> 4][(t & 15) * 8];
    bf16* vsl = &Vt[t >> 3][((t & 7) * 8) ^ (((t >> 3) & 7) << 3)];

    // Q fragments (B-operand of swapped QK^T) hoisted to registers
    bf16x8 qf[4];
    #pragma unroll
    for (int kk = 0; kk < 4; ++kk)
        qf[kk] = *(const bf16x8*)(Qb + base + (size_t)(q0 + wv * 16 + lo) * Hh + kk * 32 + hi * 8);

    f32x4 acc[8];
    #pragma unroll
    for (int f = 0; f < 8; ++f) acc[f] = f32x4{0.f, 0.f, 0.f, 0.f};
    float M_ = -INFINITY, L_ = 0.f;   // state for q-row (wv*16+lo), replicated over hi

    uint4 kr0, kr1, kr2, kr3, vr0, vr1, vr2, vr3;
#define ISSUE(T) do {                                            \
        const bf16* kp_ = kg + (size_t)(T) * (64 * Hh);          \
        kr0 = *(const uint4*)(kp_);                              \
        kr1 = *(const uint4*)(kp_ + 16 * Hh);                    \
        kr2 = *(const uint4*)(kp_ + 32 * Hh);                    \
        kr3 = *(const uint4*)(kp_ + 48 * Hh);                    \
        const bf16* vp_ = vg + (T) * 64;                         \
        vr0 = *(const uint4*)(vp_);                              \
        vr1 = *(const uint4*)(vp_ + 32 * Ss);                    \
        vr2 = *(const uint4*)(vp_ + 64 * Ss);                    \
        vr3 = *(const uint4*)(vp_ + 96 * Ss);                    \
    } while (0)

    ISSUE(c);
    for (int tile = c; tile <= qb; tile += NC) {
        __syncthreads();   // previous tile's LDS reads done
        *(uint4*)(ksl) = kr0;
        *(uint4*)(ksl + 16 * 136) = kr1;
        *(uint4*)(ksl + 32 * 136) = kr2;
        *(uint4*)(ksl + 48 * 136) = kr3;
        *(uint4*)(vsl) = vr0;
        *(uint4*)(vsl + 32 * 64) = vr1;
        *(uint4*)(vsl + 64 * 64) = vr2;
        *(uint4*)(vsl + 96 * 64) = vr3;
        const int tn = tile + NC;
        if (tn <= qb) ISSUE(tn);   // hide next tile's loads under compute
        __syncthreads();

        // S^T = K Q^T : D[kv][q], kv = f*16+hi*4+i, q = lo
        f32x4 sv[4];
        #pragma unroll
        for (int f = 0; f < 4; ++f) sv[f] = f32x4{0.f, 0.f, 0.f, 0.f};
        #pragma unroll
        for (int kk = 0; kk < 4; ++kk) {
            #pragma unroll
            for (int f = 0; f < 4; ++f) {
                bf16x8 kf = *(const bf16x8*)&Ks[f * 16 + lo][kk * 32 + hi * 8];
                sv[f] = MFMA16(kf, qf[kk], sv[f]);
            }
        }
        if (tile == qb) {   // diagonal tile: mask kv > q (local indices)
            int qg = wv * 16 + lo;
            #pragma unroll
            for (int f = 0; f < 4; ++f)
                #pragma unroll
                for (int i = 0; i < 4; ++i)
                    if (f * 16 + hi * 4 + i > qg) sv[f][i] = -INFINITY;
        }
        // online softmax: lane owns 16 kv of row q=lo; in-lane tree + 2 shuffles
        float pm = -INFINITY;
        #pragma unroll
        for (int f = 0; f < 4; ++f)
            pm = fmaxf(pm, fmaxf(fmaxf(sv[f][0], sv[f][1]), fmaxf(sv[f][2], sv[f][3])));
        pm = fmaxf(pm, __shfl_xor(pm, 16));
        pm = fmaxf(pm, __shfl_xor(pm, 32));
        float nM = fmaxf(M_, pm);
        float scn = __expf(M_ - nM);
        float rs = 0.f;
        #pragma unroll
        for (int f = 0; f < 4; ++f)
            #pragma unroll
            for (int i = 0; i < 4; ++i) {
                float e = __expf(sv[f][i] - nM);
                sv[f][i] = e;
                rs += e;
            }
        rs += __shfl_xor(rs, 16);
        rs += __shfl_xor(rs, 32);
        L_ = L_ * scn + rs;
        M_ = nM;
        // rescale O: acc row q' = hi*4+i needs scn of lane lo=q' (same hi-group)
        #pragma unroll
        for (int i = 0; i < 4; ++i) {
            float si = __shfl(scn, (lane & 48) + hi * 4 + i);
            #pragma unroll
            for (int f = 0; f < 8; ++f) acc[f][i] *= si;
        }
        // P -> wave-private LDS as P[q][kv]
        #pragma unroll
        for (int f = 0; f < 4; ++f)
            #pragma unroll
            for (int i = 0; i < 4; ++i)
                Ps[wv][lo][f * 16 + hi * 4 + i] = (bf16)sv[f][i];
        // O += P V
        #pragma unroll
        for (int kk = 0; kk < 2; ++kk) {
            bf16x8 pa = *(const bf16x8*)&Ps[wv][lo][kk * 32 + hi * 8];
            #pragma unroll
            for (int f = 0; f < 8; ++f) {
                int row = f * 16 + lo;
                bf16x8 vf = *(const bf16x8*)&Vt[row][(kk * 32 + hi * 8) ^ ((row & 7) << 3)];
                acc[f] = MFMA16(pa, vf, acc[f]);
            }
        }
    }
#undef ISSUE
    // write unnormalized partials
    const size_t pb = (((size_t)b * 64 + qb) * NC + c) * 64;
    #pragma unroll
    for (int f = 0; f < 8; ++f)
        #pragma unroll
        for (int i = 0; i < 4; ++i) {
            int row = wv * 16 + hi * 4 + i;
            Opart[(pb + row) * 128 + f * 16 + lo] = acc[f][i];
        }
    if (hi == 0) {
        Mpart[pb + wv * 16 + lo] = M_;
        Lpart[pb + wv * 16 + lo] = L_;
    }
}

// ---------------------------------------------------------------------------
// Kernel 3: combine chunk partials. grid (S/64, B), block 256.
// ---------------------------------------------------------------------------
__global__ __launch_bounds__(256) void reduce_kernel(
    const float* __restrict__ Opart, const float* __restrict__ Mpart,
    const float* __restrict__ Lpart, float* __restrict__ out, int NC)
{
    __shared__ float wexp[4][64];
    __shared__ float invL[64];
    const int qb = blockIdx.x, b = blockIdx.y, t = threadIdx.x;
    const int nact = min(NC, qb + 1);
    const size_t pb = ((size_t)b * 64 + qb) * NC * 64;
    if (t < 64) {
        float Mstar = -INFINITY;
        for (int c = 0; c < nact; ++c) Mstar = fmaxf(Mstar, Mpart[pb + c * 64 + t]);
        float Ls = 0.f;
        for (int c = 0; c < nact; ++c) {
            float wc = __expf(Mpart[pb + c * 64 + t] - Mstar);
            wexp[c][t] = wc;
            Ls += wc * Lpart[pb + c * 64 + t];
        }
        invL[t] = 1.f / Ls;
    }
    __syncthreads();
    #pragma unroll
    for (int rep = 0; rep < 8; ++rep) {
        int idx = rep * 256 + t;
        int row = idx >> 5, c4 = (idx & 31) * 4;
        float ox = 0.f, oy = 0.f, oz = 0.f, ow = 0.f;
        for (int c = 0; c < nact; ++c) {
            float wc = wexp[c][row];
            float4 v = *(const float4*)(Opart + (pb + (size_t)c * 64 + row) * 128 + c4);
            ox += wc * v.x; oy += wc * v.y; oz += wc * v.z; ow += wc * v.w;
        }
        float il = invL[row];
        float4 o = make_float4(ox * il, oy * il, oz * il, ow * il);
        *(float4*)(out + ((size_t)b * Ss + qb * 64 + row) * 128 + c4) = o;
    }
}

extern "C" void kernel_launch(void* const* d_in, const int* in_sizes, int n_in,
                              void* d_out, int out_size, void* d_ws, size_t ws_size,
                              hipStream_t stream) {
    (void)in_sizes; (void)n_in; (void)out_size;
    const float* embds = (const float*)d_in[0];
    const float* Wq = (const float*)d_in[1];
    const float* bq = (const float*)d_in[2];
    const float* Wk = (const float*)d_in[3];
    const float* bk = (const float*)d_in[4];
    const float* Wv = (const float*)d_in[5];
    const float* bv = (const float*)d_in[6];

    char* ws = (char*)d_ws;
    size_t off = 0;
    bf16* Qb  = (bf16*)(ws + off); off += (size_t)Mrows * Hh * 2;
    bf16* Kb  = (bf16*)(ws + off); off += (size_t)Mrows * Hh * 2;
    bf16* Vtg = (bf16*)(ws + off); off += (size_t)Mrows * Hh * 2;
    bf16* Wt  = (bf16*)(ws + off); off += (size_t)3 * Hh * Ee * 2;

    int NC = 4;
    {
        auto need = [&](int nc) -> size_t {
            return off + (size_t)Bb * 64 * nc * 64 * 128 * 4
                       + (size_t)Bb * 64 * nc * 64 * 4 * 2;
        };
        if (need(NC) > ws_size) NC = 2;
        if (need(NC) > ws_size) NC = 1;
    }
    float* Opart = (float*)(ws + off);
    size_t osz = (size_t)Bb * 64 * NC * 64 * 128 * 4;
    float* Mp = (float*)(ws + off + osz);
    float* Lp = Mp + (size_t)Bb * 64 * NC * 64;

    wprep_kernel<<<dim3(Ee / 16, 3), 256, 0, stream>>>(Wq, Wk, Wv, Wt);
    proj_kernel<<<dim3(Mrows / 64), 256, 0, stream>>>(embds, Wt, bq, bk, bv, Qb, Kb, Vtg);
    attn_kernel<<<dim3(Ss / 64, Bb, NC), 256, 0, stream>>>(Qb, Kb, Vtg, Opart, Mp, Lp, NC);
    reduce_kernel<<<dim3(Ss / 64, Bb), 256, 0, stream>>>(Opart, Mp, Lp, (float*)d_out, NC);
}